// Round 21
// baseline (124.460 us; speedup 1.0000x reference)
//
#include <hip/hip_runtime.h>
#include <math.h>

#define B_   20
#define S_   500
#define DIM_ 300
#define QK_  128
#define HID_ 600
#define NROW (B_ * S_)   // 10000

typedef int   v4i  __attribute__((ext_vector_type(4)));

__device__ __forceinline__ unsigned short f32_to_bf16(float f) {
  unsigned int u = __float_as_uint(f);
  unsigned int r = (u + 0x7FFFu + ((u >> 16) & 1u)) >> 16;
  return (unsigned short)r;
}
__device__ __forceinline__ float bf16_to_f32(unsigned short s) {
  return __uint_as_float(((unsigned int)s) << 16);
}

__device__ __forceinline__ float quant15(float y, float s) {
  return truncf(fminf(fmaxf(__fdiv_rn(y, s), -15.f), 15.f));
}

// ================== merged prep + LN/shift/quant ==================
__global__ __launch_bounds__(256) void k_prep_ln(
    const float* __restrict__ x,
    const float* __restrict__ g, const float* __restrict__ b,
    const float* __restrict__ qk_s, const float* __restrict__ hidden_s,
    signed char* __restrict__ xq8, signed char* __restrict__ xh8,
    float* __restrict__ sq, float* __restrict__ sh,
    const float* __restrict__ rel_emb, float* __restrict__ dbias,
    const float* __restrict__ Wh, signed char* __restrict__ q1h, float* __restrict__ s1h,
    const float* __restrict__ Wo, signed char* __restrict__ q1o, float* __restrict__ s1o,
    const float* __restrict__ Wqk, signed char* __restrict__ q1k, float* __restrict__ s1k) {
  int blk = blockIdx.x;
  int tid = threadIdx.x;
  int lane = tid & 63;
  if (blk < 2500) {
    int row = blk * 4 + (tid >> 6);
    if (row >= NROW) return;
    bool hasp = (row % S_) > 0;
    const float* xr = x + (size_t)row * DIM_;
    const float* xpr = x + (size_t)(row - 1) * DIM_;
    float xc[5], xp[5];
    #pragma unroll
    for (int i = 0; i < 5; ++i) {
      int c = lane + i * 64;
      xc[i] = (c < DIM_) ? xr[c] : 0.f;
      xp[i] = (hasp && c < DIM_) ? xpr[c] : 0.f;
    }
    float sc = 0.f, sp = 0.f;
    #pragma unroll
    for (int i = 0; i < 5; ++i) { sc += xc[i]; sp += xp[i]; }
    #pragma unroll
    for (int off = 1; off < 64; off <<= 1) {
      sc += __shfl_xor(sc, off);
      sp += __shfl_xor(sp, off);
    }
    float mu_c = sc / (float)DIM_, mu_p = sp / (float)DIM_;
    float vc = 0.f, vp = 0.f;
    #pragma unroll
    for (int i = 0; i < 5; ++i) {
      int c = lane + i * 64;
      if (c < DIM_) {
        float dc = xc[i] - mu_c; vc += dc * dc;
        float dp = xp[i] - mu_p; vp += dp * dp;
      }
    }
    #pragma unroll
    for (int off = 1; off < 64; off <<= 1) {
      vc += __shfl_xor(vc, off);
      vp += __shfl_xor(vp, off);
    }
    float den_c = sqrtf(vc / (float)DIM_ + 1e-5f);
    float den_p = sqrtf(vp / (float)DIM_ + 1e-5f);
    float yq[5], yh[5];
    float mq = 0.f, mh = 0.f;
    #pragma unroll
    for (int i = 0; i < 5; ++i) {
      int c = lane + i * 64;
      if (c < DIM_) {
        float src;
        if (c < DIM_ / 2)
          src = hasp ? __fdiv_rn(xp[i] - mu_p, den_p) * g[c] + b[c] : 0.f;
        else
          src = __fdiv_rn(xc[i] - mu_c, den_c) * g[c] + b[c];
        yq[i] = __fdiv_rn(src, qk_s[c]);
        yh[i] = __fdiv_rn(src, hidden_s[c]);
        mq = fmaxf(mq, fabsf(yq[i]));
        mh = fmaxf(mh, fabsf(yh[i]));
      }
    }
    #pragma unroll
    for (int off = 1; off < 64; off <<= 1) {
      mq = fmaxf(mq, __shfl_xor(mq, off));
      mh = fmaxf(mh, __shfl_xor(mh, off));
    }
    float sqv = mq / 15.0f, shv = mh / 15.0f;
    if (lane == 0) { sq[row] = sqv; sh[row] = shv; }
    #pragma unroll
    for (int i = 0; i < 5; ++i) {
      int c = lane + i * 64;
      if (c < DIM_) {
        xq8[(size_t)row * 320 + c] = (signed char)quant15(yq[i], sqv);
        xh8[(size_t)row * 320 + c] = (signed char)quant15(yh[i], shv);
      } else if (c < 320) {
        xq8[(size_t)row * 320 + c] = 0;
        xh8[(size_t)row * 320 + c] = 0;
      }
    }
    return;
  }
  int jidx = (blk - 2500) * 4 + (tid >> 6);
  if (jidx >= 1744) return;
  if (jidx < 16) {
    int idx = jidx * 64 + lane;
    int dd = idx - 512;
    int ret = (dd < 0) ? 16 : 0;
    int n = dd < 0 ? -dd : dd;
    int v;
    if (n < 8)       v = n;
    else if (n < 12) v = 8;
    else if (n < 16) v = 9;
    else if (n < 23) v = 10;
    else if (n < 32) v = 11;
    else if (n < 46) v = 12;
    else if (n < 64) v = 13;
    else if (n < 91) v = 14;
    else             v = 15;
    dbias[idx] = __fmul_rn(rel_emb[ret + v], 11.313708498984761f);
    return;
  }
  const float* src; signed char* q1; float* s1;
  int j, C, CP;
  if (jidx < 1296)      { j = jidx - 16;   src = Wh;  q1 = q1h; s1 = s1h; C = DIM_; CP = 320; }
  else if (jidx < 1616) { j = jidx - 1296; src = Wo;  q1 = q1o; s1 = s1o; C = HID_; CP = 640; }
  else                  { j = jidx - 1616; src = Wqk; q1 = q1k; s1 = s1k; C = DIM_; CP = 320; }
  float m = 0.f;
  for (int k = lane; k < C; k += 64) m = fmaxf(m, fabsf(src[(size_t)j * C + k]));
  #pragma unroll
  for (int off = 1; off < 64; off <<= 1) m = fmaxf(m, __shfl_xor(m, off));
  float s1v = m / 127.0f;
  float s1inv = s1v > 0.f ? 1.0f / s1v : 0.f;
  if (lane == 0) s1[j] = s1v;
  for (int k = lane; k < CP; k += 64) {
    float wv = (k < C) ? src[(size_t)j * C + k] : 0.f;
    float q1f = fminf(fmaxf(rintf(wv * s1inv), -127.f), 127.f);
    q1[(size_t)j * CP + k] = (signed char)q1f;
  }
}

// ---------- hidden GEMM, single-level i8 MFMA; 256x64 tile, grid (19,40) ----------
__global__ __launch_bounds__(512) void k_hidden(
    const signed char* __restrict__ xh8p, const float* __restrict__ sh,
    const signed char* __restrict__ q1h, const float* __restrict__ s1h,
    const float* __restrict__ bh, const float* __restrict__ hp,
    unsigned short* __restrict__ v16, unsigned short* __restrict__ gate16,
    int* __restrict__ vsmax) {
  int j0 = blockIdx.x * 64;
  int i0 = blockIdx.y * 256;
  int tid = threadIdx.x;
  int w = tid >> 6, l = tid & 63, g = l >> 4, ln = l & 15;
  int wm = w >> 1, wn = w & 1;
  __shared__ __align__(16) signed char smem[33792];
  signed char* a_lds  = smem;
  signed char* b1_lds = smem + 16384;
  unsigned short* st  = (unsigned short*)smem;

  int r0 = tid >> 2, ch0 = tid & 3;
  int r1 = r0 + 128;
  int koff0 = ((ch0 ^ ((r0 >> 1) & 3)) * 16);
  int koff1 = ((ch0 ^ ((r1 >> 1) & 3)) * 16);
  int ga0 = i0 + r0; if (ga0 >= NROW) ga0 = NROW - 1;
  int ga1 = i0 + r1; if (ga1 >= NROW) ga1 = NROW - 1;
  const signed char* srcA0 = xh8p + (size_t)ga0 * 320 + koff0;
  const signed char* srcA1 = xh8p + (size_t)ga1 * 320 + koff1;
  bool hasB = tid < 256;
  int br = (tid & 255) >> 2, bch = tid & 3;
  int bkoff = ((bch ^ ((br >> 1) & 3)) * 16);
  const signed char* srcB = q1h + (size_t)(j0 + br) * 320 + bkoff;

  v4i pa0 = *(const v4i*)srcA0;
  v4i pa1 = *(const v4i*)srcA1;
  v4i zero = {0, 0, 0, 0};
  v4i pb = hasB ? *(const v4i*)srcB : zero;

  int rxor = ((g ^ ((ln >> 1) & 3)) * 16);
  v4i acc1[4][2];
  #pragma unroll
  for (int sl = 0; sl < 4; ++sl)
    #pragma unroll
    for (int t = 0; t < 2; ++t) acc1[sl][t] = zero;

  for (int st_i = 0; st_i < 5; ++st_i) {
    *(v4i*)(a_lds + tid * 16)        = pa0;
    *(v4i*)(a_lds + 8192 + tid * 16) = pa1;
    if (hasB) *(v4i*)(b1_lds + tid * 16) = pb;
    __syncthreads();
    if (st_i < 4) {
      int k0 = (st_i + 1) * 64;
      pa0 = *(const v4i*)(srcA0 + k0);
      pa1 = *(const v4i*)(srcA1 + k0);
      if (hasB) pb = *(const v4i*)(srcB + k0);
    }
    v4i af[4];
    #pragma unroll
    for (int sl = 0; sl < 4; ++sl)
      af[sl] = *(const v4i*)(a_lds + (wm * 64 + sl * 16 + ln) * 64 + rxor);
    #pragma unroll
    for (int t = 0; t < 2; ++t) {
      int boff = (wn * 32 + t * 16 + ln) * 64 + rxor;
      v4i b1 = *(const v4i*)(b1_lds + boff);
      #pragma unroll
      for (int sl = 0; sl < 4; ++sl)
        acc1[sl][t] = __builtin_amdgcn_mfma_i32_16x16x64_i8(af[sl], b1, acc1[sl][t], 0, 0, 0);
    }
    __syncthreads();
  }
  int rbase = i0 + wm * 64;
  int b0 = rbase / S_;
  int bbound = (b0 + 1) * S_;
  int rtop = rbase + 63; if (rtop >= NROW) rtop = NROW - 1;
  int b1i = rtop / S_;
  #pragma unroll
  for (int t = 0; t < 2; ++t) {
    int col = j0 + wn * 32 + t * 16 + ln;
    int cl = wn * 32 + t * 16 + ln;
    if (col < 2 * HID_) {
      float s1v = s1h[col], bc = bh[col], hpc = hp[col];
      bool isv = col < HID_;
      float m0 = 0.f, m1 = 0.f;
      #pragma unroll
      for (int sl = 0; sl < 4; ++sl) {
        #pragma unroll
        for (int r = 0; r < 4; ++r) {
          int grow = rbase + sl * 16 + g * 4 + r;
          if (grow < NROW) {
            float z = s1v * (float)acc1[sl][t][r] + bc;
            float sig = 1.0f / (1.0f + __expf(-z));
            float val = __fmul_rn(z * sig, __fmul_rn(sh[grow], hpc));
            unsigned short hv = f32_to_bf16(val);
            st[(wm * 64 + sl * 16 + g * 4 + r) * 66 + cl] = hv;
            if (isv) {
              float vr = fabsf(bf16_to_f32(hv));
              if (grow < bbound) m0 = fmaxf(m0, vr);
              else               m1 = fmaxf(m1, vr);
            }
          }
        }
      }
      if (isv) {
        atomicMax(&vsmax[b0 * 640 + col], __float_as_int(m0));
        if (b1i != b0) atomicMax(&vsmax[b1i * 640 + col], __float_as_int(m1));
      }
    }
  }
  __syncthreads();
  for (int idx = tid; idx < 2048; idx += 512) {
    int r = idx >> 3, seg = idx & 7;
    int grow = i0 + r;
    int col0 = j0 + seg * 8;
    if (grow < NROW && col0 < 2 * HID_) {
      const unsigned int* sp = (const unsigned int*)(st + r * 66 + seg * 8);
      v4i pk;
      pk[0] = sp[0]; pk[1] = sp[1]; pk[2] = sp[2]; pk[3] = sp[3];
      if (col0 < HID_)
        *(v4i*)(v16 + (size_t)grow * HID_ + col0) = pk;
      else
        *(v4i*)(gate16 + (size_t)grow * HID_ + (col0 - HID_)) = pk;
    }
  }
}

// ---------- merged qk GEMM + v quantize/transpose (independent work) ----------
// blocks [0,157): qk (64 rows/block); [157, 157+1600): vq2 tiles.
__global__ __launch_bounds__(256) void k_qkv(
    const signed char* __restrict__ xq8p, const float* __restrict__ sq,
    const signed char* __restrict__ q1k, const float* __restrict__ s1k,
    const float* __restrict__ bqk, const float* __restrict__ qkp,
    const float* __restrict__ osg, const float* __restrict__ osb,
    signed char* __restrict__ qq8, signed char* __restrict__ kq2,
    float* __restrict__ qs, float* __restrict__ ks,
    const unsigned short* __restrict__ v16, const int* __restrict__ vsmax,
    const float* __restrict__ out_s,
    signed char* __restrict__ vqt2, float* __restrict__ vg) {
  int blk = blockIdx.x;
  int tid = threadIdx.x;
  if (blk >= 157) {
    // ---------------- vq2 ----------------
    int idx = blk - 157;
    int b = idx / 80;
    int rem = idx % 80;
    int s0 = (rem % 8) * 64;
    int d0 = (rem / 8) * 64;
    __shared__ float tile[64][65];
    int dj = tid & 63, si4 = tid >> 6;
    #pragma unroll
    for (int it = 0; it < 16; ++it) {
      int s = s0 + it * 4 + si4;
      int d = d0 + dj;
      float val = 0.f;
      if (s < S_ && d < HID_) val = bf16_to_f32(v16[((size_t)b * S_ + s) * HID_ + d]);
      tile[it * 4 + si4][dj] = val;
    }
    if (s0 == 0 && tid < 64) {
      int d = d0 + tid;
      float vsv = __int_as_float(vsmax[b * 640 + d]) / 15.0f;
      vg[b * 640 + d] = (d < HID_) ? __fdiv_rn(vsv, out_s[d]) : 0.f;
    }
    __syncthreads();
    int dd = tid >> 2, seg = tid & 3;
    int d = d0 + dd;
    int kk = s0 >> 6;
    v4i pack = {0, 0, 0, 0};
    if (d < HID_) {
      float vsv = __int_as_float(vsmax[b * 640 + d]) / 15.0f;
      signed char* pc = (signed char*)&pack;
      #pragma unroll
      for (int e = 0; e < 16; ++e)
        pc[e] = (signed char)quant15(tile[seg * 16 + e][dd], vsv);
    }
    *(v4i*)(vqt2 + ((((size_t)b * 8 + kk) * 640) + d) * 64 + seg * 16) = pack;
    return;
  }
  // ---------------- qk ----------------
  int i0 = blk * 64;
  int w = tid >> 6, l = tid & 63, g = l >> 4, ln = l & 15;
  __shared__ __align__(16) signed char a_lds[64 * 64];
  __shared__ __align__(16) signed char b1_lds[128 * 64];
  __shared__ float freqs[32];
  if (tid < 32) {
    double e = (double)(tid & ~1) / 32.0;
    freqs[tid] = (float)(1.0 / pow(10000.0, e));
  }
  int arow = tid >> 2;
  int xorb = (((tid & 3) ^ ((tid >> 3) & 3)) * 16);
  int ga = i0 + arow; if (ga >= NROW) ga = NROW - 1;
  const signed char* srcA   = xq8p + (size_t)ga * 320 + xorb;
  const signed char* srcB1a = q1k + (size_t)arow * 320 + xorb;
  const signed char* srcB1b = q1k + (size_t)(64 + arow) * 320 + xorb;
  v4i pa   = *(const v4i*)srcA;
  v4i pb1a = *(const v4i*)srcB1a, pb1b = *(const v4i*)srcB1b;
  int rxor = ((g ^ ((ln >> 1) & 3)) * 16);
  v4i acc1[8];
  v4i zero = {0, 0, 0, 0};
  #pragma unroll
  for (int t = 0; t < 8; ++t) acc1[t] = zero;
  for (int st = 0; st < 5; ++st) {
    *(v4i*)(a_lds + tid * 16)         = pa;
    *(v4i*)(b1_lds + tid * 16)        = pb1a;
    *(v4i*)(b1_lds + 4096 + tid * 16) = pb1b;
    __syncthreads();
    if (st < 4) {
      int k0 = (st + 1) * 64;
      pa   = *(const v4i*)(srcA + k0);
      pb1a = *(const v4i*)(srcB1a + k0);
      pb1b = *(const v4i*)(srcB1b + k0);
    }
    v4i af = *(const v4i*)(a_lds + (w * 16 + ln) * 64 + rxor);
    #pragma unroll
    for (int t = 0; t < 8; ++t) {
      int boff = (t * 16 + ln) * 64 + rxor;
      v4i b1 = *(const v4i*)(b1_lds + boff);
      acc1[t] = __builtin_amdgcn_mfma_i32_16x16x64_i8(af, b1, acc1[t], 0, 0, 0);
    }
    __syncthreads();
  }
  int growr[4]; float sqr[4];
  #pragma unroll
  for (int r = 0; r < 4; ++r) {
    growr[r] = i0 + w * 16 + g * 4 + r;
    int gc = growr[r] < NROW ? growr[r] : NROW - 1;
    sqr[r] = sq[gc];
  }
  float qv[8][4], kv[8][4];
  #pragma unroll
  for (int t = 0; t < 8; ++t) {
    int c = t * 16 + ln;
    float s1v = s1k[c], bc = bqk[c], qkpc = qkp[c];
    float g0 = osg[c], g1 = osg[QK_ + c], b0 = osb[c], b1v = osb[QK_ + c];
    #pragma unroll
    for (int r = 0; r < 4; ++r) {
      float z = s1v * (float)acc1[t][r] + bc;
      float sig = 1.0f / (1.0f + expf(-z));
      float qkv = __fmul_rn(z * sig, __fmul_rn(sqr[r], qkpc));
      qv[t][r] = __fadd_rn(__fmul_rn(qkv, g0), b0);
      kv[t][r] = __fadd_rn(__fmul_rn(qkv, g1), b1v);
    }
  }
  #pragma unroll
  for (int t = 0; t < 2; ++t) {
    float inv = freqs[t * 16 + ln];
    #pragma unroll
    for (int r = 0; r < 4; ++r) {
      int pos = growr[r] % S_;
      float fr = __fmul_rn((float)pos, inv);
      float cs = cosf(fr), sn = sinf(fr);
      float qo = __shfl_xor(qv[t][r], 1);
      float ko = __shfl_xor(kv[t][r], 1);
      float rq = ((ln & 1) == 0) ? -qo : qo;
      float rk = ((ln & 1) == 0) ? -ko : ko;
      qv[t][r] = __fadd_rn(__fmul_rn(qv[t][r], cs), __fmul_rn(rq, sn));
      kv[t][r] = __fadd_rn(__fmul_rn(kv[t][r], cs), __fmul_rn(rk, sn));
    }
  }
  float qsv[4], ksv[4];
  #pragma unroll
  for (int r = 0; r < 4; ++r) {
    float mq = 0.f, mk = 0.f;
    #pragma unroll
    for (int t = 0; t < 8; ++t) {
      mq = fmaxf(mq, fabsf(qv[t][r]));
      mk = fmaxf(mk, fabsf(kv[t][r]));
    }
    #pragma unroll
    for (int off = 1; off < 16; off <<= 1) {
      mq = fmaxf(mq, __shfl_xor(mq, off));
      mk = fmaxf(mk, __shfl_xor(mk, off));
    }
    qsv[r] = mq / 15.0f; ksv[r] = mk / 15.0f;
    if (ln == 0 && growr[r] < NROW) { qs[growr[r]] = qsv[r]; ks[growr[r]] = ksv[r]; }
  }
  #pragma unroll
  for (int t = 0; t < 8; ++t) {
    int c = t * 16 + ln;
    #pragma unroll
    for (int r = 0; r < 4; ++r) {
      if (growr[r] < NROW) {
        qq8[(size_t)growr[r] * QK_ + c] = (signed char)quant15(qv[t][r], qsv[r]);
        int bb = growr[r] / S_, ss = growr[r] % S_;
        kq2[(((size_t)bb * 2 + (c >> 6)) * 512 + ss) * 64 + (c & 63)] =
            (signed char)quant15(kv[t][r], ksv[r]);
      }
    }
  }
}

// ---------- fused QK^T + T5 + relu^2 + quant (LDS) + PV; 16 rows/block ----------
__global__ __launch_bounds__(512) void k_simpv(
    const signed char* __restrict__ qq8, const signed char* __restrict__ kq2,
    const float* __restrict__ qs, const float* __restrict__ ks,
    const float* __restrict__ dbias,
    const signed char* __restrict__ vqt2, const float* __restrict__ vg,
    const unsigned short* __restrict__ gate16,
    signed char* __restrict__ oq8, float* __restrict__ osc) {
  int i0 = blockIdx.x * 16;
  int b = blockIdx.y;
  int tid = threadIdx.x;
  int w = tid >> 6, l = tid & 63, g = l >> 4, ln = l & 15;
  __shared__ __align__(16) signed char q_lds[16 * 144];
  __shared__ __align__(16) signed char p_lds[16 * 528];
  __shared__ float db[1024];
  __shared__ int rowmax[16];
  if (tid < 128) {
    int r = tid >> 3, ww = tid & 7;
    *(v4i*)(q_lds + r * 144 + ww * 16) =
        *(const v4i*)(qq8 + ((size_t)(b * S_ + i0 + r)) * QK_ + ww * 16);
  }
  for (int idx = tid; idx < 1024; idx += 512) db[idx] = dbias[idx];
  if (tid < 16) rowmax[tid] = 0;
  __syncthreads();
  v4i acc[4];
  v4i zero = {0, 0, 0, 0};
  #pragma unroll
  for (int t = 0; t < 4; ++t) acc[t] = zero;
  #pragma unroll
  for (int kk = 0; kk < 2; ++kk) {
    v4i afrag = *(const v4i*)(q_lds + ln * 144 + kk * 64 + g * 16);
    #pragma unroll
    for (int t = 0; t < 4; ++t) {
      int j0 = (w * 4 + t) * 16;
      v4i bfrag = *(const v4i*)(kq2 + (((size_t)b * 2 + kk) * 512 + j0 + ln) * 64 + g * 16);
      acc[t] = __builtin_amdgcn_mfma_i32_16x16x64_i8(afrag, bfrag, acc[t], 0, 0, 0);
    }
  }
  float qsr[4];
  #pragma unroll
  for (int r = 0; r < 4; ++r) qsr[r] = qs[b * S_ + i0 + g * 4 + r];
  float rm[4] = {0.f, 0.f, 0.f, 0.f};
  #pragma unroll
  for (int t = 0; t < 4; ++t) {
    int j = (w * 4 + t) * 16 + ln;
    bool jv = j < S_;
    float ksv = ks[b * S_ + j];
    #pragma unroll
    for (int r = 0; r < 4; ++r) {
      int ip = i0 + g * 4 + r;
      float av = 0.f;
      if (jv) {
        float simv = __fmul_rn(__fmul_rn((float)acc[t][r], qsr[r]), ksv);
        simv = __fadd_rn(simv, db[ip - j + 512]);
        float rr = fmaxf(__fmul_rn(simv, 0.002f), 0.f);
        av = __fmul_rn(rr, rr);
      }
      rm[r] = fmaxf(rm[r], av);
      acc[t][r] = __float_as_int(av);
    }
  }
  #pragma unroll
  for (int r = 0; r < 4; ++r) atomicMax(&rowmax[g * 4 + r], __float_as_int(rm[r]));
  __syncthreads();
  float asr[4], rinv[4];
  #pragma unroll
  for (int r = 0; r < 4; ++r) {
    asr[r] = __int_as_float(rowmax[g * 4 + r]) / 15.0f;
    rinv[r] = __fdiv_rn(1.0f, asr[r]);
  }
  #pragma unroll
  for (int t = 0; t < 4; ++t) {
    int j = (w * 4 + t) * 16 + ln;
    #pragma unroll
    for (int r = 0; r < 4; ++r) {
      float y = __int_as_float(acc[t][r]);
      float q = truncf(fminf(fmaxf(__fmul_rn(y, rinv[r]), -15.f), 15.f));
      p_lds[(g * 4 + r) * 528 + j] = (signed char)q;
    }
  }
  __syncthreads();
  if (tid < 16) rowmax[tid] = 0;
  __syncthreads();
  v4i pacc[5];
  #pragma unroll
  for (int t = 0; t < 5; ++t) pacc[t] = zero;
  for (int kk = 0; kk < 8; ++kk) {
    v4i afrag = *(const v4i*)(p_lds + ln * 528 + kk * 64 + g * 16);
    const signed char* bbase = vqt2 + (((size_t)b * 8 + kk) * 640) * 64 + g * 16;
    #pragma unroll
    for (int t = 0; t < 5; ++t) {
      int d = (w * 5 + t) * 16 + ln;
      v4i bfrag = *(const v4i*)(bbase + (size_t)d * 64);
      pacc[t] = __builtin_amdgcn_mfma_i32_16x16x64_i8(afrag, bfrag, pacc[t], 0, 0, 0);
    }
  }
  float rm2[4] = {0.f, 0.f, 0.f, 0.f};
  #pragma unroll
  for (int t = 0; t < 5; ++t) {
    int d = (w * 5 + t) * 16 + ln;
    bool dv = d < HID_;
    float vgv = vg[b * 640 + d];
    #pragma unroll
    for (int r = 0; r < 4; ++r) {
      float o = 0.f;
      if (dv) {
        float gt = bf16_to_f32(gate16[((size_t)(b * S_ + i0 + g * 4 + r)) * HID_ + d]);
        o = __fmul_rn(__fmul_rn(__fmul_rn((float)pacc[t][r], asr[r]), vgv), gt);
      }
      rm2[r] = fmaxf(rm2[r], fabsf(o));
      pacc[t][r] = __float_as_int(o);
    }
  }
  #pragma unroll
  for (int r = 0; r < 4; ++r) atomicMax(&rowmax[g * 4 + r], __float_as_int(rm2[r]));
  __syncthreads();
  float orinv[4];
  #pragma unroll
  for (int r = 0; r < 4; ++r) {
    float osr = __int_as_float(rowmax[g * 4 + r]) / 15.0f;
    orinv[r] = __fdiv_rn(1.0f, osr);
  }
  #pragma unroll
  for (int t = 0; t < 5; ++t) {
    int d = (w * 5 + t) * 16 + ln;
    #pragma unroll
    for (int r = 0; r < 4; ++r) {
      int il = i0 + g * 4 + r;
      if (il < S_) {
        signed char valc = 0;
        if (d < HID_) {
          float q = truncf(fminf(fmaxf(
              __fmul_rn(__int_as_float(pacc[t][r]), orinv[r]), -15.f), 15.f));
          valc = (signed char)q;
        }
        oq8[((size_t)b * S_ + il) * 640 + d] = valc;
      }
    }
  }
  if (tid < 16 && i0 + tid < S_)
    osc[b * S_ + i0 + tid] = __int_as_float(rowmax[tid]) / 15.0f;
}

// ---------- output GEMM, single-level i8 MFMA, 128x64 tile + residual ----------
// grid (5, 79): j fast so the 5 consumers of each A-panel are co-resident.
__global__ __launch_bounds__(256) void k_final(
    const signed char* __restrict__ oq8p, const float* __restrict__ osc,
    const signed char* __restrict__ q1o, const float* __restrict__ s1o,
    const float* __restrict__ bo, const float* __restrict__ op,
    const float* __restrict__ x, float* __restrict__ out) {
  int j0 = blockIdx.x * 64;
  int i0 = blockIdx.y * 128;
  int tid = threadIdx.x;
  int w = tid >> 6, l = tid & 63, g = l >> 4, ln = l & 15;
  int wm = w >> 1, wn = w & 1;
  __shared__ __align__(16) signed char a_lds[128 * 64];
  __shared__ __align__(16) signed char b1_lds[64 * 64];

  int arow0 = tid >> 2;
  int xorb = (((tid & 3) ^ ((tid >> 3) & 3)) * 16);
  int ga0 = i0 + arow0;       if (ga0 >= NROW) ga0 = NROW - 1;
  int ga1 = i0 + arow0 + 64;  if (ga1 >= NROW) ga1 = NROW - 1;
  int gcol = j0 + arow0;
  const signed char* srcA0 = oq8p + (size_t)ga0 * 640 + xorb;
  const signed char* srcA1 = oq8p + (size_t)ga1 * 640 + xorb;
  const signed char* srcB1 = q1o + (size_t)gcol * 640 + xorb;

  v4i pa0 = *(const v4i*)(srcA0);
  v4i pa1 = *(const v4i*)(srcA1);
  v4i pb1 = *(const v4i*)(srcB1);

  int rxor = ((g ^ ((ln >> 1) & 3)) * 16);
  v4i acc1[4][2];
  v4i zero = {0, 0, 0, 0};
  #pragma unroll
  for (int sl = 0; sl < 4; ++sl)
    #pragma unroll
    for (int t = 0; t < 2; ++t) acc1[sl][t] = zero;

  for (int st = 0; st < 10; ++st) {
    *(v4i*)(a_lds + tid * 16)        = pa0;
    *(v4i*)(a_lds + 4096 + tid * 16) = pa1;
    *(v4i*)(b1_lds + tid * 16)       = pb1;
    __syncthreads();
    if (st < 9) {
      int k0 = (st + 1) * 64;
      pa0 = *(const v4i*)(srcA0 + k0);
      pa1 = *(const v4i*)(srcA1 + k0);
      pb1 = *(const v4i*)(srcB1 + k0);
    }
    v4i af[4];
    #pragma unroll
    for (int sl = 0; sl < 4; ++sl)
      af[sl] = *(const v4i*)(a_lds + (wm * 64 + sl * 16 + ln) * 64 + rxor);
    #pragma unroll
    for (int t = 0; t < 2; ++t) {
      int boff = (wn * 32 + t * 16 + ln) * 64 + rxor;
      v4i b1 = *(const v4i*)(b1_lds + boff);
      #pragma unroll
      for (int sl = 0; sl < 4; ++sl)
        acc1[sl][t] = __builtin_amdgcn_mfma_i32_16x16x64_i8(af[sl], b1, acc1[sl][t], 0, 0, 0);
    }
    __syncthreads();
  }
  #pragma unroll
  for (int t = 0; t < 2; ++t) {
    int col = j0 + wn * 32 + t * 16 + ln;
    if (col < DIM_) {
      float s1v = s1o[col], bc = bo[col], opc = op[col];
      #pragma unroll
      for (int sl = 0; sl < 4; ++sl) {
        #pragma unroll
        for (int r = 0; r < 4; ++r) {
          int grow = i0 + wm * 64 + sl * 16 + g * 4 + r;
          if (grow < NROW) {
            float z = s1v * (float)acc1[sl][t][r] + bc;
            float tval = __fmul_rn(osc[grow], opc);
            out[(size_t)grow * DIM_ + col] =
                __fmul_rn(z, tval) + x[(size_t)grow * DIM_ + col];
          }
        }
      }
    }
  }
}

// ---------- launch ----------
extern "C" void kernel_launch(void* const* d_in, const int* in_sizes, int n_in,
                              void* d_out, int out_size, void* d_ws, size_t ws_size,
                              hipStream_t stream) {
  const float* x        = (const float*)d_in[0];
  const float* ng       = (const float*)d_in[1];
  const float* nbt      = (const float*)d_in[2];
  const float* Wh       = (const float*)d_in[3];
  const float* bh       = (const float*)d_in[4];
  const float* Wqk      = (const float*)d_in[5];
  const float* bqk      = (const float*)d_in[6];
  const float* osg      = (const float*)d_in[7];
  const float* osb      = (const float*)d_in[8];
  const float* Wo       = (const float*)d_in[9];
  const float* bo       = (const float*)d_in[10];
  const float* rel      = (const float*)d_in[11];
  const float* qk_s     = (const float*)d_in[12];
  const float* hidden_s = (const float*)d_in[13];
  const float* out_s    = (const float*)d_in[14];
  const float* hp       = (const float*)d_in[15];
  const float* qkp      = (const float*)d_in[16];
  const float* op       = (const float*)d_in[17];
  float* out = (float*)d_out;

  char* ws = (char*)d_ws;
  size_t off = 0;
  auto alloc = [&](size_t bytes) {
    void* p = ws + off;
    off += (bytes + 255) & ~(size_t)255;
    return p;
  };
  signed char* xq8    = (signed char*)alloc((size_t)(NROW + 128) * 320);
  signed char* xh8    = (signed char*)alloc((size_t)(NROW + 256) * 320);
  float*       sq     = (float*)      alloc((size_t)(NROW + 256) * 4);
  float*       sh     = (float*)      alloc((size_t)(NROW + 256) * 4);
  unsigned short* v16   = (unsigned short*)alloc((size_t)(NROW + 256) * HID_ * 2);
  unsigned short* gate16= (unsigned short*)alloc((size_t)(NROW + 256) * HID_ * 2);
  signed char* qq8    = (signed char*)alloc((size_t)(NROW + 128) * QK_);
  signed char* kq2    = (signed char*)alloc((size_t)B_ * 2 * 512 * 64);
  float*       qs     = (float*)      alloc((size_t)(NROW + 128) * 4);
  float*       ks     = (float*)      alloc((size_t)(NROW + 128) * 4);
  signed char* vqt2   = (signed char*)alloc((size_t)B_ * 8 * 640 * 64);
  float*       vg     = (float*)      alloc((size_t)B_ * 640 * 4);
  int*         vsmax  = (int*)        alloc((size_t)B_ * 640 * 4);
  signed char* oq8    = (signed char*)alloc((size_t)(NROW + 128) * 640);
  float*       osc    = (float*)      alloc((size_t)(NROW + 128) * 4);
  float*       dbias  = (float*)      alloc((size_t)1024 * 4);
  signed char* q1h    = (signed char*)alloc((size_t)1280 * 320);
  float*       s1h    = (float*)      alloc((size_t)1280 * 4);
  signed char* q1o    = (signed char*)alloc((size_t)320 * 640);
  float*       s1o    = (float*)      alloc((size_t)320 * 4);
  signed char* q1k    = (signed char*)alloc((size_t)QK_ * 320);
  float*       s1k    = (float*)      alloc((size_t)QK_ * 4);

  // No memsets (kq2 pad rows feed masked outputs; vsmax atomicMax over
  // non-negative values with negative poison / identical stale values).

  k_prep_ln<<<2936, 256, 0, stream>>>(x, ng, nbt, qk_s, hidden_s, xq8, xh8, sq, sh,
                                      rel, dbias, Wh, q1h, s1h, Wo, q1o, s1o,
                                      Wqk, q1k, s1k);
  k_hidden<<<dim3(19, 40), 512, 0, stream>>>(xh8, sh, q1h, s1h, bh, hp,
                                             v16, gate16, vsmax);
  k_qkv<<<157 + 1600, 256, 0, stream>>>(xq8, sq, q1k, s1k, bqk, qkp, osg, osb,
                                        qq8, kq2, qs, ks,
                                        v16, vsmax, out_s, vqt2, vg);
  k_simpv<<<dim3(32, B_), 512, 0, stream>>>(qq8, kq2, qs, ks, dbias, vqt2, vg,
                                            gate16, oq8, osc);
  k_final<<<dim3(5, 79), 256, 0, stream>>>(oq8, osc, q1o, s1o, bo, op, x, out);
}

// Round 22
// 122.706 us; speedup vs baseline: 1.0143x; 1.0143x over previous
//
#include <hip/hip_runtime.h>
#include <math.h>

#define B_   20
#define S_   500
#define DIM_ 300
#define QK_  128
#define HID_ 600
#define NROW (B_ * S_)   // 10000

typedef int   v4i  __attribute__((ext_vector_type(4)));

__device__ __forceinline__ unsigned short f32_to_bf16(float f) {
  unsigned int u = __float_as_uint(f);
  unsigned int r = (u + 0x7FFFu + ((u >> 16) & 1u)) >> 16;
  return (unsigned short)r;
}
__device__ __forceinline__ float bf16_to_f32(unsigned short s) {
  return __uint_as_float(((unsigned int)s) << 16);
}

__device__ __forceinline__ float quant15(float y, float s) {
  return truncf(fminf(fmaxf(__fdiv_rn(y, s), -15.f), 15.f));
}

// ================== merged prep + LN/shift/quant ==================
__global__ __launch_bounds__(256) void k_prep_ln(
    const float* __restrict__ x,
    const float* __restrict__ g, const float* __restrict__ b,
    const float* __restrict__ qk_s, const float* __restrict__ hidden_s,
    signed char* __restrict__ xq8, signed char* __restrict__ xh8,
    float* __restrict__ sq, float* __restrict__ sh,
    const float* __restrict__ rel_emb, float* __restrict__ dbias,
    const float* __restrict__ Wh, signed char* __restrict__ q1h, float* __restrict__ s1h,
    const float* __restrict__ Wo, signed char* __restrict__ q1o, float* __restrict__ s1o,
    const float* __restrict__ Wqk, signed char* __restrict__ q1k, float* __restrict__ s1k) {
  int blk = blockIdx.x;
  int tid = threadIdx.x;
  int lane = tid & 63;
  if (blk < 2500) {
    int row = blk * 4 + (tid >> 6);
    if (row >= NROW) return;
    bool hasp = (row % S_) > 0;
    const float* xr = x + (size_t)row * DIM_;
    const float* xpr = x + (size_t)(row - 1) * DIM_;
    float xc[5], xp[5];
    #pragma unroll
    for (int i = 0; i < 5; ++i) {
      int c = lane + i * 64;
      xc[i] = (c < DIM_) ? xr[c] : 0.f;
      xp[i] = (hasp && c < DIM_) ? xpr[c] : 0.f;
    }
    float sc = 0.f, sp = 0.f;
    #pragma unroll
    for (int i = 0; i < 5; ++i) { sc += xc[i]; sp += xp[i]; }
    #pragma unroll
    for (int off = 1; off < 64; off <<= 1) {
      sc += __shfl_xor(sc, off);
      sp += __shfl_xor(sp, off);
    }
    float mu_c = sc / (float)DIM_, mu_p = sp / (float)DIM_;
    float vc = 0.f, vp = 0.f;
    #pragma unroll
    for (int i = 0; i < 5; ++i) {
      int c = lane + i * 64;
      if (c < DIM_) {
        float dc = xc[i] - mu_c; vc += dc * dc;
        float dp = xp[i] - mu_p; vp += dp * dp;
      }
    }
    #pragma unroll
    for (int off = 1; off < 64; off <<= 1) {
      vc += __shfl_xor(vc, off);
      vp += __shfl_xor(vp, off);
    }
    float den_c = sqrtf(vc / (float)DIM_ + 1e-5f);
    float den_p = sqrtf(vp / (float)DIM_ + 1e-5f);
    float yq[5], yh[5];
    float mq = 0.f, mh = 0.f;
    #pragma unroll
    for (int i = 0; i < 5; ++i) {
      int c = lane + i * 64;
      if (c < DIM_) {
        float src;
        if (c < DIM_ / 2)
          src = hasp ? __fdiv_rn(xp[i] - mu_p, den_p) * g[c] + b[c] : 0.f;
        else
          src = __fdiv_rn(xc[i] - mu_c, den_c) * g[c] + b[c];
        yq[i] = __fdiv_rn(src, qk_s[c]);
        yh[i] = __fdiv_rn(src, hidden_s[c]);
        mq = fmaxf(mq, fabsf(yq[i]));
        mh = fmaxf(mh, fabsf(yh[i]));
      }
    }
    #pragma unroll
    for (int off = 1; off < 64; off <<= 1) {
      mq = fmaxf(mq, __shfl_xor(mq, off));
      mh = fmaxf(mh, __shfl_xor(mh, off));
    }
    float sqv = mq / 15.0f, shv = mh / 15.0f;
    if (lane == 0) { sq[row] = sqv; sh[row] = shv; }
    #pragma unroll
    for (int i = 0; i < 5; ++i) {
      int c = lane + i * 64;
      if (c < DIM_) {
        xq8[(size_t)row * 320 + c] = (signed char)quant15(yq[i], sqv);
        xh8[(size_t)row * 320 + c] = (signed char)quant15(yh[i], shv);
      } else if (c < 320) {
        xq8[(size_t)row * 320 + c] = 0;
        xh8[(size_t)row * 320 + c] = 0;
      }
    }
    return;
  }
  int jidx = (blk - 2500) * 4 + (tid >> 6);
  if (jidx >= 1744) return;
  if (jidx < 16) {
    int idx = jidx * 64 + lane;
    int dd = idx - 512;
    int ret = (dd < 0) ? 16 : 0;
    int n = dd < 0 ? -dd : dd;
    int v;
    if (n < 8)       v = n;
    else if (n < 12) v = 8;
    else if (n < 16) v = 9;
    else if (n < 23) v = 10;
    else if (n < 32) v = 11;
    else if (n < 46) v = 12;
    else if (n < 64) v = 13;
    else if (n < 91) v = 14;
    else             v = 15;
    dbias[idx] = __fmul_rn(rel_emb[ret + v], 11.313708498984761f);
    return;
  }
  const float* src; signed char* q1; float* s1;
  int j, C, CP;
  if (jidx < 1296)      { j = jidx - 16;   src = Wh;  q1 = q1h; s1 = s1h; C = DIM_; CP = 320; }
  else if (jidx < 1616) { j = jidx - 1296; src = Wo;  q1 = q1o; s1 = s1o; C = HID_; CP = 640; }
  else                  { j = jidx - 1616; src = Wqk; q1 = q1k; s1 = s1k; C = DIM_; CP = 320; }
  float m = 0.f;
  for (int k = lane; k < C; k += 64) m = fmaxf(m, fabsf(src[(size_t)j * C + k]));
  #pragma unroll
  for (int off = 1; off < 64; off <<= 1) m = fmaxf(m, __shfl_xor(m, off));
  float s1v = m / 127.0f;
  float s1inv = s1v > 0.f ? 1.0f / s1v : 0.f;
  if (lane == 0) s1[j] = s1v;
  for (int k = lane; k < CP; k += 64) {
    float wv = (k < C) ? src[(size_t)j * C + k] : 0.f;
    float q1f = fminf(fmaxf(rintf(wv * s1inv), -127.f), 127.f);
    q1[(size_t)j * CP + k] = (signed char)q1f;
  }
}

// ---------- hidden GEMM, single-level i8 MFMA; 256x64 tile; XCD-swizzled ----------
// grid 760 (= 8 * 95): each XCD gets a contiguous 95-block chunk of work space,
// so the 19 j-blocks sharing an A-panel land on the same XCD's L2.
__global__ __launch_bounds__(512) void k_hidden(
    const signed char* __restrict__ xh8p, const float* __restrict__ sh,
    const signed char* __restrict__ q1h, const float* __restrict__ s1h,
    const float* __restrict__ bh, const float* __restrict__ hp,
    unsigned short* __restrict__ v16, unsigned short* __restrict__ gate16,
    int* __restrict__ vsmax) {
  int orig = blockIdx.x;
  int swz = (orig & 7) * 95 + (orig >> 3);   // bijective: 760 = 8*95
  int j0 = (swz % 19) * 64;
  int i0 = (swz / 19) * 256;
  int tid = threadIdx.x;
  int w = tid >> 6, l = tid & 63, g = l >> 4, ln = l & 15;
  int wm = w >> 1, wn = w & 1;
  __shared__ __align__(16) signed char smem[33792];
  signed char* a_lds  = smem;
  signed char* b1_lds = smem + 16384;
  unsigned short* st  = (unsigned short*)smem;

  int r0 = tid >> 2, ch0 = tid & 3;
  int r1 = r0 + 128;
  int koff0 = ((ch0 ^ ((r0 >> 1) & 3)) * 16);
  int koff1 = ((ch0 ^ ((r1 >> 1) & 3)) * 16);
  int ga0 = i0 + r0; if (ga0 >= NROW) ga0 = NROW - 1;
  int ga1 = i0 + r1; if (ga1 >= NROW) ga1 = NROW - 1;
  const signed char* srcA0 = xh8p + (size_t)ga0 * 320 + koff0;
  const signed char* srcA1 = xh8p + (size_t)ga1 * 320 + koff1;
  bool hasB = tid < 256;
  int br = (tid & 255) >> 2, bch = tid & 3;
  int bkoff = ((bch ^ ((br >> 1) & 3)) * 16);
  const signed char* srcB = q1h + (size_t)(j0 + br) * 320 + bkoff;

  v4i pa0 = *(const v4i*)srcA0;
  v4i pa1 = *(const v4i*)srcA1;
  v4i zero = {0, 0, 0, 0};
  v4i pb = hasB ? *(const v4i*)srcB : zero;

  int rxor = ((g ^ ((ln >> 1) & 3)) * 16);
  v4i acc1[4][2];
  #pragma unroll
  for (int sl = 0; sl < 4; ++sl)
    #pragma unroll
    for (int t = 0; t < 2; ++t) acc1[sl][t] = zero;

  for (int st_i = 0; st_i < 5; ++st_i) {
    *(v4i*)(a_lds + tid * 16)        = pa0;
    *(v4i*)(a_lds + 8192 + tid * 16) = pa1;
    if (hasB) *(v4i*)(b1_lds + tid * 16) = pb;
    __syncthreads();
    if (st_i < 4) {
      int k0 = (st_i + 1) * 64;
      pa0 = *(const v4i*)(srcA0 + k0);
      pa1 = *(const v4i*)(srcA1 + k0);
      if (hasB) pb = *(const v4i*)(srcB + k0);
    }
    v4i af[4];
    #pragma unroll
    for (int sl = 0; sl < 4; ++sl)
      af[sl] = *(const v4i*)(a_lds + (wm * 64 + sl * 16 + ln) * 64 + rxor);
    #pragma unroll
    for (int t = 0; t < 2; ++t) {
      int boff = (wn * 32 + t * 16 + ln) * 64 + rxor;
      v4i b1 = *(const v4i*)(b1_lds + boff);
      #pragma unroll
      for (int sl = 0; sl < 4; ++sl)
        acc1[sl][t] = __builtin_amdgcn_mfma_i32_16x16x64_i8(af[sl], b1, acc1[sl][t], 0, 0, 0);
    }
    __syncthreads();
  }
  int rbase = i0 + wm * 64;
  int b0 = rbase / S_;
  int bbound = (b0 + 1) * S_;
  int rtop = rbase + 63; if (rtop >= NROW) rtop = NROW - 1;
  int b1i = rtop / S_;
  #pragma unroll
  for (int t = 0; t < 2; ++t) {
    int col = j0 + wn * 32 + t * 16 + ln;
    int cl = wn * 32 + t * 16 + ln;
    if (col < 2 * HID_) {
      float s1v = s1h[col], bc = bh[col], hpc = hp[col];
      bool isv = col < HID_;
      float m0 = 0.f, m1 = 0.f;
      #pragma unroll
      for (int sl = 0; sl < 4; ++sl) {
        #pragma unroll
        for (int r = 0; r < 4; ++r) {
          int grow = rbase + sl * 16 + g * 4 + r;
          if (grow < NROW) {
            float z = s1v * (float)acc1[sl][t][r] + bc;
            float sig = 1.0f / (1.0f + __expf(-z));
            float val = __fmul_rn(z * sig, __fmul_rn(sh[grow], hpc));
            unsigned short hv = f32_to_bf16(val);
            st[(wm * 64 + sl * 16 + g * 4 + r) * 66 + cl] = hv;
            if (isv) {
              float vr = fabsf(bf16_to_f32(hv));
              if (grow < bbound) m0 = fmaxf(m0, vr);
              else               m1 = fmaxf(m1, vr);
            }
          }
        }
      }
      if (isv) {
        atomicMax(&vsmax[b0 * 640 + col], __float_as_int(m0));
        if (b1i != b0) atomicMax(&vsmax[b1i * 640 + col], __float_as_int(m1));
      }
    }
  }
  __syncthreads();
  for (int idx = tid; idx < 2048; idx += 512) {
    int r = idx >> 3, seg = idx & 7;
    int grow = i0 + r;
    int col0 = j0 + seg * 8;
    if (grow < NROW && col0 < 2 * HID_) {
      const unsigned int* sp = (const unsigned int*)(st + r * 66 + seg * 8);
      v4i pk;
      pk[0] = sp[0]; pk[1] = sp[1]; pk[2] = sp[2]; pk[3] = sp[3];
      if (col0 < HID_)
        *(v4i*)(v16 + (size_t)grow * HID_ + col0) = pk;
      else
        *(v4i*)(gate16 + (size_t)grow * HID_ + (col0 - HID_)) = pk;
    }
  }
}

// ---------- merged qk GEMM + v quantize/transpose (independent work) ----------
// blocks [0,157): qk (64 rows/block); [157, 157+1600): vq2 tiles.
__global__ __launch_bounds__(256) void k_qkv(
    const signed char* __restrict__ xq8p, const float* __restrict__ sq,
    const signed char* __restrict__ q1k, const float* __restrict__ s1k,
    const float* __restrict__ bqk, const float* __restrict__ qkp,
    const float* __restrict__ osg, const float* __restrict__ osb,
    signed char* __restrict__ qq8, signed char* __restrict__ kq2,
    float* __restrict__ qs, float* __restrict__ ks,
    const unsigned short* __restrict__ v16, const int* __restrict__ vsmax,
    const float* __restrict__ out_s,
    signed char* __restrict__ vqt2, float* __restrict__ vg) {
  int blk = blockIdx.x;
  int tid = threadIdx.x;
  if (blk >= 157) {
    // ---------------- vq2 ----------------
    int idx = blk - 157;
    int b = idx / 80;
    int rem = idx % 80;
    int s0 = (rem % 8) * 64;
    int d0 = (rem / 8) * 64;
    __shared__ float tile[64][65];
    int dj = tid & 63, si4 = tid >> 6;
    #pragma unroll
    for (int it = 0; it < 16; ++it) {
      int s = s0 + it * 4 + si4;
      int d = d0 + dj;
      float val = 0.f;
      if (s < S_ && d < HID_) val = bf16_to_f32(v16[((size_t)b * S_ + s) * HID_ + d]);
      tile[it * 4 + si4][dj] = val;
    }
    if (s0 == 0 && tid < 64) {
      int d = d0 + tid;
      float vsv = __int_as_float(vsmax[b * 640 + d]) / 15.0f;
      vg[b * 640 + d] = (d < HID_) ? __fdiv_rn(vsv, out_s[d]) : 0.f;
    }
    __syncthreads();
    int dd = tid >> 2, seg = tid & 3;
    int d = d0 + dd;
    int kk = s0 >> 6;
    v4i pack = {0, 0, 0, 0};
    if (d < HID_) {
      float vsv = __int_as_float(vsmax[b * 640 + d]) / 15.0f;
      signed char* pc = (signed char*)&pack;
      #pragma unroll
      for (int e = 0; e < 16; ++e)
        pc[e] = (signed char)quant15(tile[seg * 16 + e][dd], vsv);
    }
    *(v4i*)(vqt2 + ((((size_t)b * 8 + kk) * 640) + d) * 64 + seg * 16) = pack;
    return;
  }
  // ---------------- qk ----------------
  int i0 = blk * 64;
  int w = tid >> 6, l = tid & 63, g = l >> 4, ln = l & 15;
  __shared__ __align__(16) signed char a_lds[64 * 64];
  __shared__ __align__(16) signed char b1_lds[128 * 64];
  __shared__ float freqs[32];
  if (tid < 32) {
    double e = (double)(tid & ~1) / 32.0;
    freqs[tid] = (float)(1.0 / pow(10000.0, e));
  }
  int arow = tid >> 2;
  int xorb = (((tid & 3) ^ ((tid >> 3) & 3)) * 16);
  int ga = i0 + arow; if (ga >= NROW) ga = NROW - 1;
  const signed char* srcA   = xq8p + (size_t)ga * 320 + xorb;
  const signed char* srcB1a = q1k + (size_t)arow * 320 + xorb;
  const signed char* srcB1b = q1k + (size_t)(64 + arow) * 320 + xorb;
  v4i pa   = *(const v4i*)srcA;
  v4i pb1a = *(const v4i*)srcB1a, pb1b = *(const v4i*)srcB1b;
  int rxor = ((g ^ ((ln >> 1) & 3)) * 16);
  v4i acc1[8];
  v4i zero = {0, 0, 0, 0};
  #pragma unroll
  for (int t = 0; t < 8; ++t) acc1[t] = zero;
  for (int st = 0; st < 5; ++st) {
    *(v4i*)(a_lds + tid * 16)         = pa;
    *(v4i*)(b1_lds + tid * 16)        = pb1a;
    *(v4i*)(b1_lds + 4096 + tid * 16) = pb1b;
    __syncthreads();
    if (st < 4) {
      int k0 = (st + 1) * 64;
      pa   = *(const v4i*)(srcA + k0);
      pb1a = *(const v4i*)(srcB1a + k0);
      pb1b = *(const v4i*)(srcB1b + k0);
    }
    v4i af = *(const v4i*)(a_lds + (w * 16 + ln) * 64 + rxor);
    #pragma unroll
    for (int t = 0; t < 8; ++t) {
      int boff = (t * 16 + ln) * 64 + rxor;
      v4i b1 = *(const v4i*)(b1_lds + boff);
      acc1[t] = __builtin_amdgcn_mfma_i32_16x16x64_i8(af, b1, acc1[t], 0, 0, 0);
    }
    __syncthreads();
  }
  int growr[4]; float sqr[4];
  #pragma unroll
  for (int r = 0; r < 4; ++r) {
    growr[r] = i0 + w * 16 + g * 4 + r;
    int gc = growr[r] < NROW ? growr[r] : NROW - 1;
    sqr[r] = sq[gc];
  }
  float qv[8][4], kv[8][4];
  #pragma unroll
  for (int t = 0; t < 8; ++t) {
    int c = t * 16 + ln;
    float s1v = s1k[c], bc = bqk[c], qkpc = qkp[c];
    float g0 = osg[c], g1 = osg[QK_ + c], b0 = osb[c], b1v = osb[QK_ + c];
    #pragma unroll
    for (int r = 0; r < 4; ++r) {
      float z = s1v * (float)acc1[t][r] + bc;
      float sig = 1.0f / (1.0f + expf(-z));
      float qkv = __fmul_rn(z * sig, __fmul_rn(sqr[r], qkpc));
      qv[t][r] = __fadd_rn(__fmul_rn(qkv, g0), b0);
      kv[t][r] = __fadd_rn(__fmul_rn(qkv, g1), b1v);
    }
  }
  #pragma unroll
  for (int t = 0; t < 2; ++t) {
    float inv = freqs[t * 16 + ln];
    #pragma unroll
    for (int r = 0; r < 4; ++r) {
      int pos = growr[r] % S_;
      float fr = __fmul_rn((float)pos, inv);
      float cs = cosf(fr), sn = sinf(fr);
      float qo = __shfl_xor(qv[t][r], 1);
      float ko = __shfl_xor(kv[t][r], 1);
      float rq = ((ln & 1) == 0) ? -qo : qo;
      float rk = ((ln & 1) == 0) ? -ko : ko;
      qv[t][r] = __fadd_rn(__fmul_rn(qv[t][r], cs), __fmul_rn(rq, sn));
      kv[t][r] = __fadd_rn(__fmul_rn(kv[t][r], cs), __fmul_rn(rk, sn));
    }
  }
  float qsv[4], ksv[4];
  #pragma unroll
  for (int r = 0; r < 4; ++r) {
    float mq = 0.f, mk = 0.f;
    #pragma unroll
    for (int t = 0; t < 8; ++t) {
      mq = fmaxf(mq, fabsf(qv[t][r]));
      mk = fmaxf(mk, fabsf(kv[t][r]));
    }
    #pragma unroll
    for (int off = 1; off < 16; off <<= 1) {
      mq = fmaxf(mq, __shfl_xor(mq, off));
      mk = fmaxf(mk, __shfl_xor(mk, off));
    }
    qsv[r] = mq / 15.0f; ksv[r] = mk / 15.0f;
    if (ln == 0 && growr[r] < NROW) { qs[growr[r]] = qsv[r]; ks[growr[r]] = ksv[r]; }
  }
  #pragma unroll
  for (int t = 0; t < 8; ++t) {
    int c = t * 16 + ln;
    #pragma unroll
    for (int r = 0; r < 4; ++r) {
      if (growr[r] < NROW) {
        qq8[(size_t)growr[r] * QK_ + c] = (signed char)quant15(qv[t][r], qsv[r]);
        int bb = growr[r] / S_, ss = growr[r] % S_;
        kq2[(((size_t)bb * 2 + (c >> 6)) * 512 + ss) * 64 + (c & 63)] =
            (signed char)quant15(kv[t][r], ksv[r]);
      }
    }
  }
}

// ---------- fused QK^T + T5 + relu^2 + quant (LDS) + PV; 16 rows/block ----------
// grid 640 (= 8 * 80), XCD-swizzled: blocks of the same batch share kq2/vqt2.
__global__ __launch_bounds__(512) void k_simpv(
    const signed char* __restrict__ qq8, const signed char* __restrict__ kq2,
    const float* __restrict__ qs, const float* __restrict__ ks,
    const float* __restrict__ dbias,
    const signed char* __restrict__ vqt2, const float* __restrict__ vg,
    const unsigned short* __restrict__ gate16,
    signed char* __restrict__ oq8, float* __restrict__ osc) {
  int orig = blockIdx.x;
  int swz = (orig & 7) * 80 + (orig >> 3);   // bijective: 640 = 8*80
  int b = swz / 32;
  int i0 = (swz % 32) * 16;
  int tid = threadIdx.x;
  int w = tid >> 6, l = tid & 63, g = l >> 4, ln = l & 15;
  __shared__ __align__(16) signed char q_lds[16 * 144];
  __shared__ __align__(16) signed char p_lds[16 * 528];
  __shared__ float db[1024];
  __shared__ int rowmax[16];
  if (tid < 128) {
    int r = tid >> 3, ww = tid & 7;
    *(v4i*)(q_lds + r * 144 + ww * 16) =
        *(const v4i*)(qq8 + ((size_t)(b * S_ + i0 + r)) * QK_ + ww * 16);
  }
  for (int idx = tid; idx < 1024; idx += 512) db[idx] = dbias[idx];
  if (tid < 16) rowmax[tid] = 0;
  __syncthreads();
  v4i acc[4];
  v4i zero = {0, 0, 0, 0};
  #pragma unroll
  for (int t = 0; t < 4; ++t) acc[t] = zero;
  #pragma unroll
  for (int kk = 0; kk < 2; ++kk) {
    v4i afrag = *(const v4i*)(q_lds + ln * 144 + kk * 64 + g * 16);
    #pragma unroll
    for (int t = 0; t < 4; ++t) {
      int j0 = (w * 4 + t) * 16;
      v4i bfrag = *(const v4i*)(kq2 + (((size_t)b * 2 + kk) * 512 + j0 + ln) * 64 + g * 16);
      acc[t] = __builtin_amdgcn_mfma_i32_16x16x64_i8(afrag, bfrag, acc[t], 0, 0, 0);
    }
  }
  float qsr[4];
  #pragma unroll
  for (int r = 0; r < 4; ++r) qsr[r] = qs[b * S_ + i0 + g * 4 + r];
  float rm[4] = {0.f, 0.f, 0.f, 0.f};
  #pragma unroll
  for (int t = 0; t < 4; ++t) {
    int j = (w * 4 + t) * 16 + ln;
    bool jv = j < S_;
    float ksv = ks[b * S_ + j];
    #pragma unroll
    for (int r = 0; r < 4; ++r) {
      int ip = i0 + g * 4 + r;
      float av = 0.f;
      if (jv) {
        float simv = __fmul_rn(__fmul_rn((float)acc[t][r], qsr[r]), ksv);
        simv = __fadd_rn(simv, db[ip - j + 512]);
        float rr = fmaxf(__fmul_rn(simv, 0.002f), 0.f);
        av = __fmul_rn(rr, rr);
      }
      rm[r] = fmaxf(rm[r], av);
      acc[t][r] = __float_as_int(av);
    }
  }
  #pragma unroll
  for (int r = 0; r < 4; ++r) atomicMax(&rowmax[g * 4 + r], __float_as_int(rm[r]));
  __syncthreads();
  float asr[4], rinv[4];
  #pragma unroll
  for (int r = 0; r < 4; ++r) {
    asr[r] = __int_as_float(rowmax[g * 4 + r]) / 15.0f;
    rinv[r] = __fdiv_rn(1.0f, asr[r]);
  }
  #pragma unroll
  for (int t = 0; t < 4; ++t) {
    int j = (w * 4 + t) * 16 + ln;
    #pragma unroll
    for (int r = 0; r < 4; ++r) {
      float y = __int_as_float(acc[t][r]);
      float q = truncf(fminf(fmaxf(__fmul_rn(y, rinv[r]), -15.f), 15.f));
      p_lds[(g * 4 + r) * 528 + j] = (signed char)q;
    }
  }
  __syncthreads();
  if (tid < 16) rowmax[tid] = 0;
  __syncthreads();
  v4i pacc[5];
  #pragma unroll
  for (int t = 0; t < 5; ++t) pacc[t] = zero;
  for (int kk = 0; kk < 8; ++kk) {
    v4i afrag = *(const v4i*)(p_lds + ln * 528 + kk * 64 + g * 16);
    const signed char* bbase = vqt2 + (((size_t)b * 8 + kk) * 640) * 64 + g * 16;
    #pragma unroll
    for (int t = 0; t < 5; ++t) {
      int d = (w * 5 + t) * 16 + ln;
      v4i bfrag = *(const v4i*)(bbase + (size_t)d * 64);
      pacc[t] = __builtin_amdgcn_mfma_i32_16x16x64_i8(afrag, bfrag, pacc[t], 0, 0, 0);
    }
  }
  float rm2[4] = {0.f, 0.f, 0.f, 0.f};
  #pragma unroll
  for (int t = 0; t < 5; ++t) {
    int d = (w * 5 + t) * 16 + ln;
    bool dv = d < HID_;
    float vgv = vg[b * 640 + d];
    #pragma unroll
    for (int r = 0; r < 4; ++r) {
      float o = 0.f;
      if (dv) {
        float gt = bf16_to_f32(gate16[((size_t)(b * S_ + i0 + g * 4 + r)) * HID_ + d]);
        o = __fmul_rn(__fmul_rn(__fmul_rn((float)pacc[t][r], asr[r]), vgv), gt);
      }
      rm2[r] = fmaxf(rm2[r], fabsf(o));
      pacc[t][r] = __float_as_int(o);
    }
  }
  #pragma unroll
  for (int r = 0; r < 4; ++r) atomicMax(&rowmax[g * 4 + r], __float_as_int(rm2[r]));
  __syncthreads();
  float orinv[4];
  #pragma unroll
  for (int r = 0; r < 4; ++r) {
    float osr = __int_as_float(rowmax[g * 4 + r]) / 15.0f;
    orinv[r] = __fdiv_rn(1.0f, osr);
  }
  #pragma unroll
  for (int t = 0; t < 5; ++t) {
    int d = (w * 5 + t) * 16 + ln;
    #pragma unroll
    for (int r = 0; r < 4; ++r) {
      int il = i0 + g * 4 + r;
      if (il < S_) {
        signed char valc = 0;
        if (d < HID_) {
          float q = truncf(fminf(fmaxf(
              __fmul_rn(__int_as_float(pacc[t][r]), orinv[r]), -15.f), 15.f));
          valc = (signed char)q;
        }
        oq8[((size_t)b * S_ + il) * 640 + d] = valc;
      }
    }
  }
  if (tid < 16 && i0 + tid < S_)
    osc[b * S_ + i0 + tid] = __int_as_float(rowmax[tid]) / 15.0f;
}

// ---------- output GEMM, single-level i8 MFMA, 128x64 tile + residual ----------
// grid 395 (= 8*49 + 3), bijective XCD chunking; j fast within work space.
__global__ __launch_bounds__(256) void k_final(
    const signed char* __restrict__ oq8p, const float* __restrict__ osc,
    const signed char* __restrict__ q1o, const float* __restrict__ s1o,
    const float* __restrict__ bo, const float* __restrict__ op,
    const float* __restrict__ x, float* __restrict__ out) {
  int orig = blockIdx.x;
  int xcd = orig & 7, pos = orig >> 3;
  const int q = 49, r = 3;                   // 395 = 8*49 + 3
  int base = (xcd < r) ? xcd * (q + 1) : r * (q + 1) + (xcd - r) * q;
  int swz = base + pos;
  int j0 = (swz % 5) * 64;
  int i0 = (swz / 5) * 128;
  int tid = threadIdx.x;
  int w = tid >> 6, l = tid & 63, g = l >> 4, ln = l & 15;
  int wm = w >> 1, wn = w & 1;
  __shared__ __align__(16) signed char a_lds[128 * 64];
  __shared__ __align__(16) signed char b1_lds[64 * 64];

  int arow0 = tid >> 2;
  int xorb = (((tid & 3) ^ ((tid >> 3) & 3)) * 16);
  int ga0 = i0 + arow0;       if (ga0 >= NROW) ga0 = NROW - 1;
  int ga1 = i0 + arow0 + 64;  if (ga1 >= NROW) ga1 = NROW - 1;
  int gcol = j0 + arow0;
  const signed char* srcA0 = oq8p + (size_t)ga0 * 640 + xorb;
  const signed char* srcA1 = oq8p + (size_t)ga1 * 640 + xorb;
  const signed char* srcB1 = q1o + (size_t)gcol * 640 + xorb;

  v4i pa0 = *(const v4i*)(srcA0);
  v4i pa1 = *(const v4i*)(srcA1);
  v4i pb1 = *(const v4i*)(srcB1);

  int rxor = ((g ^ ((ln >> 1) & 3)) * 16);
  v4i acc1[4][2];
  v4i zero = {0, 0, 0, 0};
  #pragma unroll
  for (int sl = 0; sl < 4; ++sl)
    #pragma unroll
    for (int t = 0; t < 2; ++t) acc1[sl][t] = zero;

  for (int st = 0; st < 10; ++st) {
    *(v4i*)(a_lds + tid * 16)        = pa0;
    *(v4i*)(a_lds + 4096 + tid * 16) = pa1;
    *(v4i*)(b1_lds + tid * 16)       = pb1;
    __syncthreads();
    if (st < 9) {
      int k0 = (st + 1) * 64;
      pa0 = *(const v4i*)(srcA0 + k0);
      pa1 = *(const v4i*)(srcA1 + k0);
      pb1 = *(const v4i*)(srcB1 + k0);
    }
    v4i af[4];
    #pragma unroll
    for (int sl = 0; sl < 4; ++sl)
      af[sl] = *(const v4i*)(a_lds + (wm * 64 + sl * 16 + ln) * 64 + rxor);
    #pragma unroll
    for (int t = 0; t < 2; ++t) {
      int boff = (wn * 32 + t * 16 + ln) * 64 + rxor;
      v4i b1 = *(const v4i*)(b1_lds + boff);
      #pragma unroll
      for (int sl = 0; sl < 4; ++sl)
        acc1[sl][t] = __builtin_amdgcn_mfma_i32_16x16x64_i8(af[sl], b1, acc1[sl][t], 0, 0, 0);
    }
    __syncthreads();
  }
  #pragma unroll
  for (int t = 0; t < 2; ++t) {
    int col = j0 + wn * 32 + t * 16 + ln;
    if (col < DIM_) {
      float s1v = s1o[col], bc = bo[col], opc = op[col];
      #pragma unroll
      for (int sl = 0; sl < 4; ++sl) {
        #pragma unroll
        for (int r2 = 0; r2 < 4; ++r2) {
          int grow = i0 + wm * 64 + sl * 16 + g * 4 + r2;
          if (grow < NROW) {
            float z = s1v * (float)acc1[sl][t][r2] + bc;
            float tval = __fmul_rn(osc[grow], opc);
            out[(size_t)grow * DIM_ + col] =
                __fmul_rn(z, tval) + x[(size_t)grow * DIM_ + col];
          }
        }
      }
    }
  }
}

// ---------- launch ----------
extern "C" void kernel_launch(void* const* d_in, const int* in_sizes, int n_in,
                              void* d_out, int out_size, void* d_ws, size_t ws_size,
                              hipStream_t stream) {
  const float* x        = (const float*)d_in[0];
  const float* ng       = (const float*)d_in[1];
  const float* nbt      = (const float*)d_in[2];
  const float* Wh       = (const float*)d_in[3];
  const float* bh       = (const float*)d_in[4];
  const float* Wqk      = (const float*)d_in[5];
  const float* bqk      = (const float*)d_in[6];
  const float* osg      = (const float*)d_in[7];
  const float* osb      = (const float*)d_in[8];
  const float* Wo       = (const float*)d_in[9];
  const float* bo       = (const float*)d_in[10];
  const float* rel      = (const float*)d_in[11];
  const float* qk_s     = (const float*)d_in[12];
  const float* hidden_s = (const float*)d_in[13];
  const float* out_s    = (const float*)d_in[14];
  const float* hp       = (const float*)d_in[15];
  const float* qkp      = (const float*)d_in[16];
  const float* op       = (const float*)d_in[17];
  float* out = (float*)d_out;

  char* ws = (char*)d_ws;
  size_t off = 0;
  auto alloc = [&](size_t bytes) {
    void* p = ws + off;
    off += (bytes + 255) & ~(size_t)255;
    return p;
  };
  signed char* xq8    = (signed char*)alloc((size_t)(NROW + 128) * 320);
  signed char* xh8    = (signed char*)alloc((size_t)(NROW + 256) * 320);
  float*       sq     = (float*)      alloc((size_t)(NROW + 256) * 4);
  float*       sh     = (float*)      alloc((size_t)(NROW + 256) * 4);
  unsigned short* v16   = (unsigned short*)alloc((size_t)(NROW + 256) * HID_ * 2);
  unsigned short* gate16= (unsigned short*)alloc((size_t)(NROW + 256) * HID_ * 2);
  signed char* qq8    = (signed char*)alloc((size_t)(NROW + 128) * QK_);
  signed char* kq2    = (signed char*)alloc((size_t)B_ * 2 * 512 * 64);
  float*       qs     = (float*)      alloc((size_t)(NROW + 128) * 4);
  float*       ks     = (float*)      alloc((size_t)(NROW + 128) * 4);
  signed char* vqt2   = (signed char*)alloc((size_t)B_ * 8 * 640 * 64);
  float*       vg     = (float*)      alloc((size_t)B_ * 640 * 4);
  int*         vsmax  = (int*)        alloc((size_t)B_ * 640 * 4);
  signed char* oq8    = (signed char*)alloc((size_t)(NROW + 128) * 640);
  float*       osc    = (float*)      alloc((size_t)(NROW + 128) * 4);
  float*       dbias  = (float*)      alloc((size_t)1024 * 4);
  signed char* q1h    = (signed char*)alloc((size_t)1280 * 320);
  float*       s1h    = (float*)      alloc((size_t)1280 * 4);
  signed char* q1o    = (signed char*)alloc((size_t)320 * 640);
  float*       s1o    = (float*)      alloc((size_t)320 * 4);
  signed char* q1k    = (signed char*)alloc((size_t)QK_ * 320);
  float*       s1k    = (float*)      alloc((size_t)QK_ * 4);

  // No memsets (kq2 pad rows feed masked outputs; vsmax atomicMax over
  // non-negative values with negative poison / identical stale values).

  k_prep_ln<<<2936, 256, 0, stream>>>(x, ng, nbt, qk_s, hidden_s, xq8, xh8, sq, sh,
                                      rel, dbias, Wh, q1h, s1h, Wo, q1o, s1o,
                                      Wqk, q1k, s1k);
  k_hidden<<<760, 512, 0, stream>>>(xh8, sh, q1h, s1h, bh, hp,
                                    v16, gate16, vsmax);
  k_qkv<<<157 + 1600, 256, 0, stream>>>(xq8, sq, q1k, s1k, bqk, qkp, osg, osb,
                                        qq8, kq2, qs, ks,
                                        v16, vsmax, out_s, vqt2, vg);
  k_simpv<<<640, 512, 0, stream>>>(qq8, kq2, qs, ks, dbias, vqt2, vg,
                                   gate16, oq8, osc);
  k_final<<<395, 256, 0, stream>>>(oq8, osc, q1o, s1o, bo, op, x, out);
}